// Round 9
// baseline (206.488 us; speedup 1.0000x reference)
//
#include <hip/hip_runtime.h>
#include <hip/hip_bf16.h>
#include <math.h>

#define NH   12
#define HD   64
#define HID  768
#define NB   4
#define SS   2048
#define MR   (NB*SS)   // 8192 rows

#define NXE  (MR*HID)        // x elems        6291456
#define NWE  (HID*HID)       // one W elems     589824

typedef unsigned short u16;
typedef u16   u16x8  __attribute__((ext_vector_type(8)));
typedef __bf16 bf16x8 __attribute__((ext_vector_type(8)));
typedef float f32x4  __attribute__((ext_vector_type(4)));

__device__ __forceinline__ float hi2f(unsigned u) {
    union { unsigned i; float f; } c; c.i = u & 0xffff0000u; return c.f;
}
__device__ __forceinline__ float lo2f(unsigned u) {
    union { unsigned i; float f; } c; c.i = u << 16; return c.f;
}
__device__ __forceinline__ u16 f2b(float f) {
    union { float f; unsigned i; } c; c.f = f;
    unsigned x = c.i + 0x7fffu + ((c.i >> 16) & 1u);   // RNE
    return (u16)(x >> 16);
}
__device__ __forceinline__ unsigned pk2(float lo, float hi) {
    float2 f; f.x = lo; f.y = hi;
    union { __hip_bfloat162 h; unsigned u; } c;
    c.h = __float22bfloat162_rn(f);
    return c.u;
}
__device__ __forceinline__ f32x4 mfma16(u16x8 a, u16x8 b, f32x4 c) {
    return __builtin_amdgcn_mfma_f32_16x16x32_bf16(
        __builtin_bit_cast(bf16x8, a), __builtin_bit_cast(bf16x8, b), c, 0, 0, 0);
}
__device__ __forceinline__ void g2l16(const u16* g, u16* l) {
    __builtin_amdgcn_global_load_lds(
        (const __attribute__((address_space(1))) void*)g,
        (__attribute__((address_space(3))) void*)l, 16, 0, 0);
}
// pi: stored-row permutation for K (inverse of fragment key map g)
__device__ __forceinline__ int kperm(int k) {
    return ((k >> 5) << 5) | (((k >> 2) & 1) << 4) | (((k >> 3) & 3) << 2) | (k & 3);
}

// -------- one-time fp32 -> bf16 conversion of x and the three W matrices ----
__global__ __launch_bounds__(256) void to_bf16(
    const float* __restrict__ x,  const float* __restrict__ Wq,
    const float* __restrict__ Wk, const float* __restrict__ Wv,
    u16* __restrict__ dst)
{
    const int NX4 = NXE / 4, NW4 = NWE / 4, NT4 = NX4 + 3 * NW4;
    for (int i = blockIdx.x * 256 + threadIdx.x; i < NT4; i += gridDim.x * 256) {
        const float* src; u16* d;
        if (i < NX4) { src = x + (size_t)i * 4; d = dst + (size_t)i * 4; }
        else {
            int j = i - NX4; int w = j / NW4; int r = j - w * NW4;
            const float* Ws = (w == 0) ? Wq : ((w == 1) ? Wk : Wv);
            src = Ws + (size_t)r * 4; d = dst + NXE + (size_t)w * NWE + (size_t)r * 4;
        }
        float4 f = *(const float4*)src;
        uint2 o; o.x = pk2(f.x, f.y); o.y = pk2(f.z, f.w);
        *(uint2*)d = o;
    }
}

// -------- QKV projection: 128x128 tile, global_load_lds staging -------------
// Epilogue bakes attn's per-kt prep in once:
//   wsel 0 (Q): pre-scaled by 0.125/ln2 (exp2-domain softmax)
//   wsel 1 (K): rows pi-permuted within each 64-row group
//   wsel 2 (V): stored TRANSPOSED per (b,h): vt[((b*NH+h)*HD+d)*SS + s]
__global__ __launch_bounds__(256, 3) void qkv_proj(
    const u16* __restrict__ xb, const u16* __restrict__ Wb,
    const float* __restrict__ bq, const float* __restrict__ bk,
    const float* __restrict__ bv, u16* __restrict__ qkv)
{
    const int wsel = blockIdx.z;
    const u16* W = Wb + (size_t)wsel * NWE;
    const float* bias = (wsel == 0) ? bq : ((wsel == 1) ? bk : bv);
    u16* out = qkv + (size_t)wsel * MR * HID;

    const int m0 = blockIdx.x * 128, n0 = blockIdx.y * 128;
    __shared__ __align__(16) u16 As[128][32];
    __shared__ __align__(16) u16 Bs[128][32];

    const int tid  = threadIdx.x;
    const int lane = tid & 63, wid = tid >> 6;
    const int quad = lane >> 4, l16 = lane & 15;
    const int wm = wid >> 1, wn = wid & 1;

    const int rA = 2 * wid * 16 + (lane >> 2);
    const int colh = (lane & 3) * 8;
    const u16* gx0 = xb + (size_t)(m0 + rA) * HID + colh;
    const u16* gx1 = gx0 + (size_t)16 * HID;
    const u16* gw0 = W  + (size_t)(n0 + rA) * HID + colh;
    const u16* gw1 = gw0 + (size_t)16 * HID;
    u16* lA0 = &As[0][0] + (2 * wid) * 512 + lane * 8;
    u16* lA1 = lA0 + 512;
    u16* lB0 = &Bs[0][0] + (2 * wid) * 512 + lane * 8;
    u16* lB1 = lB0 + 512;

    f32x4 acc[4][4] = {};

    for (int k0 = 0; k0 < HID; k0 += 32) {
        g2l16(gx0 + k0, lA0); g2l16(gx1 + k0, lA1);
        g2l16(gw0 + k0, lB0); g2l16(gw1 + k0, lB1);
        __syncthreads();
        u16x8 af[4], bf[4];
        #pragma unroll
        for (int i = 0; i < 4; i++) af[i] = *(const u16x8*)&As[wm * 64 + i * 16 + l16][quad * 8];
        #pragma unroll
        for (int j = 0; j < 4; j++) bf[j] = *(const u16x8*)&Bs[wn * 64 + j * 16 + l16][quad * 8];
        #pragma unroll
        for (int i = 0; i < 4; i++)
            #pragma unroll
            for (int j = 0; j < 4; j++)
                acc[i][j] = mfma16(af[i], bf[j], acc[i][j]);
        __syncthreads();
    }

    if (wsel == 2) {
        // V^T scatter: 4 consecutive s per uint2 (r-packed)
        const int bidx = m0 >> 11;
        const int s0 = (m0 & 2047) + wm * 64;
        #pragma unroll
        for (int j = 0; j < 4; j++) {
            const int col = n0 + wn * 64 + j * 16 + l16;
            const float bb = bias[col];
            const int hh = col >> 6, d = col & 63;
            u16* vrow = out + ((size_t)(bidx * NH + hh) * HD + d) * SS;
            #pragma unroll
            for (int i = 0; i < 4; i++) {
                uint2 pk;
                pk.x = pk2(acc[i][j][0] + bb, acc[i][j][1] + bb);
                pk.y = pk2(acc[i][j][2] + bb, acc[i][j][3] + bb);
                *(uint2*)(vrow + s0 + i * 16 + quad * 4) = pk;
            }
        }
    } else {
        const float scale = (wsel == 0) ? 0.18033688f : 1.0f;   // 0.125/ln2 for Q
        #pragma unroll
        for (int j = 0; j < 4; j++) {
            const int col = n0 + wn * 64 + j * 16 + l16;
            const float bb = bias[col];
            #pragma unroll
            for (int i = 0; i < 4; i++)
                #pragma unroll
                for (int r = 0; r < 4; r++) {
                    int row = m0 + wm * 64 + i * 16 + quad * 4 + r;
                    if (wsel == 1) row = (row & ~63) | kperm(row & 63);
                    out[(size_t)row * HID + col] = f2b((acc[i][j][r] + bb) * scale);
                }
        }
    }
}

// -------- Flash attention, S^T form; all per-kt prep pre-baked --------------
// Q arrives pre-scaled, K rows pre-permuted, V pre-transposed: staging is
// 4 uint4 loads + 4 b128 LDS writes per thread per kt. P^T never leaves
// registers (pkd dwords ARE the PV B-operand). Fixed-shift exp2(s-6) softmax.
__global__ __launch_bounds__(256, 3) void attn(
    const u16* __restrict__ qkv, float* __restrict__ out)
{
    const int q0 = blockIdx.x * 128;
    const int h  = blockIdx.y;
    const int b  = blockIdx.z;

    const u16* qb  = qkv + (size_t)b * SS * HID + h * HD;
    const u16* kb  = qkv + (size_t)MR * HID + (size_t)b * SS * HID + h * HD;
    const u16* vtb = qkv + (size_t)2 * MR * HID + ((size_t)(b * NH + h) * HD) * SS;
    float*     ob  = out + (size_t)b * SS * HID + h * HD;

    __shared__ __align__(16) u16 Ks[64][72];   // permuted key rows x hd
    __shared__ __align__(16) u16 Vt[64][72];   // d x keys (true key order)

    const int tid  = threadIdx.x;
    const int lane = tid & 63, wid = tid >> 6;
    const int quad = lane >> 4, l16 = lane & 15;
    const int srow = tid >> 3, scg = tid & 7;

    // Q fragments: direct load (pre-scaled bf16)
    u16x8 qf[2][2];
    #pragma unroll
    for (int t = 0; t < 2; t++) {
        const int row = q0 + t * 64 + wid * 16 + l16;
        #pragma unroll
        for (int hh = 0; hh < 2; hh++)
            qf[t][hh] = *(const u16x8*)(qb + (size_t)row * HID + hh * 32 + quad * 8);
    }

    f32x4 o2[2][4] = {};
    float lsum[2] = {0.f, 0.f};

    for (int kt = 0; kt < SS / 64; kt++) {
        #pragma unroll
        for (int r2 = 0; r2 < 2; r2++) {
            const int rr = r2 * 32 + srow;
            *(uint4*)&Ks[rr][scg * 8] =
                *(const uint4*)(kb + (size_t)(kt * 64 + rr) * HID + scg * 8);
            *(uint4*)&Vt[rr][scg * 8] =
                *(const uint4*)(vtb + (size_t)rr * SS + kt * 64 + scg * 8);
        }
        __syncthreads();

        u16x8 kf[4][2];
        #pragma unroll
        for (int n = 0; n < 4; n++)
            #pragma unroll
            for (int hh = 0; hh < 2; hh++)
                kf[n][hh] = *(const u16x8*)&Ks[n * 16 + l16][hh * 32 + quad * 8];

        unsigned pkd[2][4][2];
        #pragma unroll
        for (int t = 0; t < 2; t++)
            #pragma unroll
            for (int n = 0; n < 4; n++) {
                f32x4 s = {};
                s = mfma16(kf[n][0], qf[t][0], s);
                s = mfma16(kf[n][1], qf[t][1], s);
                const float p0 = __builtin_amdgcn_exp2f(s[0] - 6.0f);
                const float p1 = __builtin_amdgcn_exp2f(s[1] - 6.0f);
                const float p2 = __builtin_amdgcn_exp2f(s[2] - 6.0f);
                const float p3 = __builtin_amdgcn_exp2f(s[3] - 6.0f);
                const unsigned w01 = pk2(p0, p1);
                const unsigned w23 = pk2(p2, p3);
                pkd[t][n][0] = w01; pkd[t][n][1] = w23;
                lsum[t] += (lo2f(w01) + hi2f(w01)) + (lo2f(w23) + hi2f(w23));
            }

        u16x8 vf[4][2];
        #pragma unroll
        for (int n2 = 0; n2 < 4; n2++)
            #pragma unroll
            for (int hh = 0; hh < 2; hh++)
                vf[n2][hh] = *(const u16x8*)&Vt[n2 * 16 + l16][hh * 32 + quad * 8];

        #pragma unroll
        for (int t = 0; t < 2; t++) {
            union { u16x8 v; unsigned d[4]; } bf0, bf1;
            bf0.d[0] = pkd[t][0][0]; bf0.d[1] = pkd[t][0][1];
            bf0.d[2] = pkd[t][1][0]; bf0.d[3] = pkd[t][1][1];
            bf1.d[0] = pkd[t][2][0]; bf1.d[1] = pkd[t][2][1];
            bf1.d[2] = pkd[t][3][0]; bf1.d[3] = pkd[t][3][1];
            #pragma unroll
            for (int n2 = 0; n2 < 4; n2++) {
                o2[t][n2] = mfma16(vf[n2][0], bf0.v, o2[t][n2]);
                o2[t][n2] = mfma16(vf[n2][1], bf1.v, o2[t][n2]);
            }
        }
        __syncthreads();
    }

    #pragma unroll
    for (int t = 0; t < 2; t++) {
        float rs = lsum[t];
        rs += __shfl_xor(rs, 16);
        rs += __shfl_xor(rs, 32);
        const float inv = 1.f / rs;
        const int q = q0 + t * 64 + wid * 16 + l16;
        #pragma unroll
        for (int n2 = 0; n2 < 4; n2++) {
            f32x4 w = o2[t][n2];
            w[0] *= inv; w[1] *= inv; w[2] *= inv; w[3] *= inv;
            *(f32x4*)(ob + (size_t)q * HID + n2 * 16 + quad * 4) = w;
        }
    }
}

extern "C" void kernel_launch(void* const* d_in, const int* in_sizes, int n_in,
                              void* d_out, int out_size, void* d_ws, size_t ws_size,
                              hipStream_t stream) {
    const float* x  = (const float*)d_in[0];
    const float* Wq = (const float*)d_in[1];
    const float* bq = (const float*)d_in[2];
    const float* Wk = (const float*)d_in[3];
    const float* bk = (const float*)d_in[4];
    const float* Wv = (const float*)d_in[5];
    const float* bv = (const float*)d_in[6];
    float* out = (float*)d_out;
    u16* qkv = (u16*)d_ws;               // 36 MB scratch: Q | K(perm) | V^T
    u16* cvt = (u16*)d_out;              // bf16 x|Wq|Wk|Wv staged in output buf

    to_bf16<<<1024, 256, 0, stream>>>(x, Wq, Wk, Wv, cvt);

    dim3 gp(MR / 128, HID / 128, 3);    // 64 x 6 x 3
    qkv_proj<<<gp, 256, 0, stream>>>(cvt, cvt + NXE, bq, bk, bv, qkv);

    dim3 ga(SS / 128, NH, NB);          // 16 x 12 x 4
    attn<<<ga, 256, 0, stream>>>(qkv, out);
}